// Round 1
// baseline (389.926 us; speedup 1.0000x reference)
//
#include <hip/hip_runtime.h>

// VectorQuantizer forward:
//   x          [64,32,32,64] f32  -> flat [N=65536, D=64]
//   embeddings [D=64, K=512] f32  (codes are COLUMNS)
//   out        = x + (q - x)  where q = column argmin_k ||f - e_k||^2
//   loss       = (1 + 0.25) * mean((q - x)^2)
// d_out = [out (4194304 f32), loss (1 f32)]

#define N_ROWS 65536
#define DIM 64
#define KCODES 512

// ws layout (bytes):
//   [0,8)      double loss accumulator
//   [256,2304) en2[512] f32
//   [4096, 4096+131072) eT[512][64] f32

__global__ void vq_prep(const float* __restrict__ emb, float* __restrict__ ws_f,
                        double* __restrict__ ws_d) {
    int k = threadIdx.x;  // 512 threads, one per code
    if (k == 0) ws_d[0] = 0.0;
    float* en2 = ws_f + 64;    // byte offset 256
    float* eT  = ws_f + 1024;  // byte offset 4096
    float s = 0.0f;
    #pragma unroll
    for (int d = 0; d < DIM; ++d) {
        float v = emb[d * KCODES + k];   // coalesced across k
        eT[k * DIM + d] = v;
        s = fmaf(v, v, s);
    }
    en2[k] = s;
}

__global__ __launch_bounds__(512)
void vq_main(const float* __restrict__ x, const float* __restrict__ ws_f,
             float* __restrict__ out, double* __restrict__ loss_acc) {
    const int tid  = threadIdx.x;     // 0..511
    const int half = tid >> 8;        // wave-uniform: waves 0-3 -> 0, 4-7 -> 1
    const int r    = tid & 255;       // row within block
    const int row  = blockIdx.x * 256 + r;

    const float*  en2 = ws_f + 64;
    const float4* eT4 = (const float4*)(ws_f + 1024);

    // Load this thread's row into registers (16 x float4 = 64 f32).
    const float4* xr = (const float4*)(x + (size_t)row * DIM);
    float4 f[16];
    #pragma unroll
    for (int j = 0; j < 16; ++j) f[j] = xr[j];

    // r2 = ||f||^2
    float4 a = make_float4(0.f, 0.f, 0.f, 0.f);
    #pragma unroll
    for (int j = 0; j < 16; ++j) {
        a.x = fmaf(f[j].x, f[j].x, a.x);
        a.y = fmaf(f[j].y, f[j].y, a.y);
        a.z = fmaf(f[j].z, f[j].z, a.z);
        a.w = fmaf(f[j].w, f[j].w, a.w);
    }
    const float r2 = (a.x + a.y) + (a.z + a.w);

    // Scan this wave-group's half of the codebook. k is wave-uniform ->
    // eT/en2 reads become scalar loads.
    const int kbase = half << 8;
    float best = 3.402823466e38f;
    int   bidx = 0;
    for (int kk = 0; kk < 256; ++kk) {
        const int k = kbase + kk;
        const float4* ek = eT4 + k * 16;
        float4 acc = make_float4(0.f, 0.f, 0.f, 0.f);
        #pragma unroll
        for (int j = 0; j < 16; ++j) {
            float4 e = ek[j];
            acc.x = fmaf(f[j].x, e.x, acc.x);
            acc.y = fmaf(f[j].y, e.y, acc.y);
            acc.z = fmaf(f[j].z, e.z, acc.z);
            acc.w = fmaf(f[j].w, e.w, acc.w);
        }
        const float dot = (acc.x + acc.y) + (acc.z + acc.w);
        const float s = (r2 + en2[k]) - 2.0f * dot;
        if (s < best) { best = s; bidx = k; }   // strict <: first index wins
    }

    // Combine the two K-halves (half 0 owns lower indices -> ties go to it).
    __shared__ float sval[256];
    __shared__ int   sidx[256];
    if (half == 1) { sval[r] = best; sidx[r] = bidx; }
    __syncthreads();

    if (half == 0) {
        const float vB = sval[r];
        const int   iB = sidx[r];
        if (vB < best) { best = vB; bidx = iB; }

        // Gather code, write out = x + (q - x), accumulate loss.
        const float4* q4 = eT4 + bidx * 16;
        float4* o4 = (float4*)(out + (size_t)row * DIM);
        float lsum = 0.0f;
        #pragma unroll
        for (int j = 0; j < 16; ++j) {
            float4 q  = q4[j];
            float4 xv = f[j];
            float4 o;
            float dx;
            dx = q.x - xv.x; o.x = xv.x + dx; lsum = fmaf(dx, dx, lsum);
            dx = q.y - xv.y; o.y = xv.y + dx; lsum = fmaf(dx, dx, lsum);
            dx = q.z - xv.z; o.z = xv.z + dx; lsum = fmaf(dx, dx, lsum);
            dx = q.w - xv.w; o.w = xv.w + dx; lsum = fmaf(dx, dx, lsum);
            o4[j] = o;
        }

        // Wave-level reduction of loss in double, one atomic per wave.
        double dl = (double)lsum;
        #pragma unroll
        for (int off = 32; off > 0; off >>= 1)
            dl += __shfl_down(dl, off);
        if ((tid & 63) == 0) atomicAdd(loss_acc, dl);
    }
}

__global__ void vq_fin(const double* __restrict__ loss_acc, float* __restrict__ out) {
    if (threadIdx.x == 0)
        out[N_ROWS * DIM] = (float)(1.25 * loss_acc[0] * (1.0 / (double)(N_ROWS * DIM)));
}

extern "C" void kernel_launch(void* const* d_in, const int* in_sizes, int n_in,
                              void* d_out, int out_size, void* d_ws, size_t ws_size,
                              hipStream_t stream) {
    const float* x   = (const float*)d_in[0];
    const float* emb = (const float*)d_in[1];
    float*  out    = (float*)d_out;
    float*  ws_f   = (float*)d_ws;
    double* ws_d   = (double*)d_ws;

    vq_prep<<<1, 512, 0, stream>>>(emb, ws_f, ws_d);
    vq_main<<<N_ROWS / 256, 512, 0, stream>>>(x, ws_f, out, ws_d);
    vq_fin<<<1, 1, 0, stream>>>(ws_d, out);
}

// Round 2
// 80.146 us; speedup vs baseline: 4.8652x; 4.8652x over previous
//
#include <hip/hip_runtime.h>

// VectorQuantizer forward:
//   x          [64,32,32,64] f32  -> flat [N=65536, D=64]
//   embeddings [D=64, K=512] f32  (codes are COLUMNS)
//   out        = x + (q - x)  where q = column argmin_k ||f - e_k||^2
//   loss       = (1 + 0.25) * mean((q - x)^2)
// d_out = [out (4194304 f32), loss (1 f32)]

#define N_ROWS 65536
#define DIM 64
#define KCODES 512
#define KGROUPS 4
#define KCHUNK 128          // codes per wave-group
#define ROWS_PER_BLOCK 64   // one wave's worth of rows; 4 waves share them K-split

// ws layout (bytes):
//   [0,8)      double loss accumulator
//   [256,2304) en2[512] f32
//   [4096, 4096+131072) eT[512][64] f32

__global__ void vq_prep(const float* __restrict__ emb, float* __restrict__ ws_f,
                        double* __restrict__ ws_d) {
    int k = threadIdx.x;  // 512 threads, one per code
    if (k == 0) ws_d[0] = 0.0;
    float* en2 = ws_f + 64;    // byte offset 256
    float* eT  = ws_f + 1024;  // byte offset 4096
    float s = 0.0f;
    #pragma unroll
    for (int d = 0; d < DIM; ++d) {
        float v = emb[d * KCODES + k];   // coalesced across k
        eT[k * DIM + d] = v;
        s = fmaf(v, v, s);
    }
    en2[k] = s;
}

__global__ __launch_bounds__(256, 4)
void vq_main(const float* __restrict__ x, const float* __restrict__ ws_f,
             float* __restrict__ out, double* __restrict__ loss_acc) {
    const int tid = threadIdx.x;                               // 0..255
    const int g   = __builtin_amdgcn_readfirstlane(tid >> 6);  // wave id = K-group (SGPR!)
    const int r   = tid & 63;                                  // row within block
    const int row = blockIdx.x * ROWS_PER_BLOCK + r;

    // Load this thread's row into registers (16 x float4 = 64 f32).
    const float4* xr = (const float4*)(x + (size_t)row * DIM);
    float4 f[16];
    #pragma unroll
    for (int j = 0; j < 16; ++j) f[j] = xr[j];

    // r2 = ||f||^2
    float4 a = make_float4(0.f, 0.f, 0.f, 0.f);
    #pragma unroll
    for (int j = 0; j < 16; ++j) {
        a.x = fmaf(f[j].x, f[j].x, a.x);
        a.y = fmaf(f[j].y, f[j].y, a.y);
        a.z = fmaf(f[j].z, f[j].z, a.z);
        a.w = fmaf(f[j].w, f[j].w, a.w);
    }
    const float r2 = (a.x + a.y) + (a.z + a.w);

    // Wave-uniform codebook chunk pointers -> compiler should emit s_load,
    // e-values live in SGPRs, FMAs take the SGPR operand directly.
    const float* __restrict__ eg   = ws_f + 1024 + (size_t)g * KCHUNK * DIM;
    const float* __restrict__ en2g = ws_f + 64 + g * KCHUNK;

    float best = 3.402823466e38f;
    int   bk   = 0;
    #pragma unroll 2
    for (int kk = 0; kk < KCHUNK; ++kk) {
        const float* __restrict__ ek = eg + kk * DIM;  // uniform address
        float4 acc = make_float4(0.f, 0.f, 0.f, 0.f);
        #pragma unroll
        for (int j = 0; j < 16; ++j) {
            acc.x = fmaf(f[j].x, ek[4 * j + 0], acc.x);
            acc.y = fmaf(f[j].y, ek[4 * j + 1], acc.y);
            acc.z = fmaf(f[j].z, ek[4 * j + 2], acc.z);
            acc.w = fmaf(f[j].w, ek[4 * j + 3], acc.w);
        }
        const float dot = (acc.x + acc.y) + (acc.z + acc.w);
        const float s = (r2 + en2g[kk]) - 2.0f * dot;
        if (s < best) { best = s; bk = kk; }   // strict <: first index wins
    }
    int bidx = g * KCHUNK + bk;                // absolute code index

    // Combine the 4 K-groups; iterate in increasing group order with strict <
    // so the lowest index wins ties (matches np.argmin).
    __shared__ float sv[KGROUPS - 1][64];
    __shared__ int   si[KGROUPS - 1][64];
    if (g > 0) { sv[g - 1][r] = best; si[g - 1][r] = bidx; }
    __syncthreads();

    if (g == 0) {
        #pragma unroll
        for (int t = 0; t < KGROUPS - 1; ++t) {
            const float v = sv[t][r];
            const int   i = si[t][r];
            if (v < best) { best = v; bidx = i; }
        }

        // Gather code, write out = x + (q - x), accumulate loss.
        const float4* q4 = (const float4*)(ws_f + 1024) + bidx * 16;
        float4* o4 = (float4*)(out + (size_t)row * DIM);
        float lsum = 0.0f;
        #pragma unroll
        for (int j = 0; j < 16; ++j) {
            float4 q  = q4[j];
            float4 xv = f[j];
            float4 o;
            float dx;
            dx = q.x - xv.x; o.x = xv.x + dx; lsum = fmaf(dx, dx, lsum);
            dx = q.y - xv.y; o.y = xv.y + dx; lsum = fmaf(dx, dx, lsum);
            dx = q.z - xv.z; o.z = xv.z + dx; lsum = fmaf(dx, dx, lsum);
            dx = q.w - xv.w; o.w = xv.w + dx; lsum = fmaf(dx, dx, lsum);
            o4[j] = o;
        }

        // Wave-level reduction of loss in double, one atomic per block.
        double dl = (double)lsum;
        #pragma unroll
        for (int off = 32; off > 0; off >>= 1)
            dl += __shfl_down(dl, off);
        if (r == 0) atomicAdd(loss_acc, dl);
    }
}

__global__ void vq_fin(const double* __restrict__ loss_acc, float* __restrict__ out) {
    if (threadIdx.x == 0)
        out[N_ROWS * DIM] = (float)(1.25 * loss_acc[0] * (1.0 / (double)(N_ROWS * DIM)));
}

extern "C" void kernel_launch(void* const* d_in, const int* in_sizes, int n_in,
                              void* d_out, int out_size, void* d_ws, size_t ws_size,
                              hipStream_t stream) {
    const float* x   = (const float*)d_in[0];
    const float* emb = (const float*)d_in[1];
    float*  out  = (float*)d_out;
    float*  ws_f = (float*)d_ws;
    double* ws_d = (double*)d_ws;

    vq_prep<<<1, 512, 0, stream>>>(emb, ws_f, ws_d);
    vq_main<<<N_ROWS / ROWS_PER_BLOCK, 256, 0, stream>>>(x, ws_f, out, ws_d);
    vq_fin<<<1, 1, 0, stream>>>(ws_d, out);
}